// Round 1
// baseline (63.856 us; speedup 1.0000x reference)
//
#include <hip/hip_runtime.h>

#define D 256
#define THREADS 256  // 4 waves per block

// ---------------------------------------------------------------------------
// DensityLoss forward, collapsed from O(C^2 D) to O(C D):
//   t[d]   = sum_i centers[i][d]
//   S      = sum_i ||c_i||^2
//   cd[i]  = (C*||c_i||^2 + S - 2*c_i.t) / (C-1)     (diagonal term is 0)
//   out    = (sum cd / C) / var(cd, ddof=1) / N
// All reductions are fixed-order (wave shuffle butterflies + serial partial
// sums) -> fully deterministic, no atomics, no ws zero-init needed (every ws
// word is written before it is read, every call).
// ---------------------------------------------------------------------------

// K1: per-wave partial column sums t_part[wave][D] and partial sum-of-squares
// S_part[wave]. Wave w handles rows [w*rpw, (w+1)*rpw); lane l owns
// d = 4l..4l+3 via float4 loads (coalesced 1 KiB per row per wave).
__global__ __launch_bounds__(THREADS) void k1_colsum(
    const float* __restrict__ centers, float* __restrict__ t_part,
    float* __restrict__ S_part, int C, int nw) {
  const int wave = (blockIdx.x * THREADS + threadIdx.x) >> 6;
  const int lane = threadIdx.x & 63;
  const int rpw = C / nw;
  const float4* src =
      (const float4*)centers + (size_t)(wave * rpw) * (D / 4) + lane;
  float4 t = make_float4(0.f, 0.f, 0.f, 0.f);
  float ss = 0.f;
  for (int r = 0; r < rpw; ++r) {
    float4 v = src[(size_t)r * (D / 4)];
    t.x += v.x; t.y += v.y; t.z += v.z; t.w += v.w;
    ss += v.x * v.x + v.y * v.y + v.z * v.z + v.w * v.w;
  }
  ((float4*)t_part)[wave * (D / 4) + lane] = t;
  for (int off = 32; off; off >>= 1) ss += __shfl_xor(ss, off, 64);
  if (lane == 0) S_part[wave] = ss;
}

// K2: reduce t_part -> t (in registers), S_part -> S (same serial order on
// every lane => identical value), then per row compute
//   u = sum_d (C*v_d - 2*t_d)*v_d  ( = C*sq[i] - 2*g[i] )
// via one wave butterfly; accumulate cd and cd^2 in double per wave.
__global__ __launch_bounds__(THREADS) void k2_cd(
    const float* __restrict__ centers, const float* __restrict__ t_part,
    const float* __restrict__ S_part, double* __restrict__ cd_part,
    double* __restrict__ cd2_part, int C, int nw) {
  const int wave = (blockIdx.x * THREADS + threadIdx.x) >> 6;
  const int lane = threadIdx.x & 63;
  // t[4l..4l+3] = sum over nw partials (L2-resident, heavily shared reads)
  float4 t = make_float4(0.f, 0.f, 0.f, 0.f);
  const float4* tp = (const float4*)t_part + lane;
  for (int p = 0; p < nw; ++p) {
    float4 v = tp[p * (D / 4)];
    t.x += v.x; t.y += v.y; t.z += v.z; t.w += v.w;
  }
  float S = 0.f;
  for (int p = 0; p < nw; ++p) S += S_part[p];  // broadcast loads, fixed order
  const float Cf = (float)C;
  const int rpw = C / nw;
  const float4* src =
      (const float4*)centers + (size_t)(wave * rpw) * (D / 4) + lane;
  const double inv = 1.0 / (double)(C - 1);
  double cds = 0.0, cd2 = 0.0;
  for (int r = 0; r < rpw; ++r) {
    float4 v = src[(size_t)r * (D / 4)];
    float u = (Cf * v.x - 2.f * t.x) * v.x + (Cf * v.y - 2.f * t.y) * v.y +
              (Cf * v.z - 2.f * t.z) * v.z + (Cf * v.w - 2.f * t.w) * v.w;
    for (int off = 32; off; off >>= 1) u += __shfl_xor(u, off, 64);
    if (lane == 0) {
      double cd = ((double)u + (double)S) * inv;
      cds += cd;
      cd2 += cd * cd;
    }
  }
  if (lane == 0) {
    cd_part[wave] = cds;
    cd2_part[wave] = cd2;
  }
}

// K3: combine nw double partials -> scalar output.
__global__ void k3_final(const double* __restrict__ cd_part,
                         const double* __restrict__ cd2_part,
                         float* __restrict__ out, int C, long long N, int nw) {
  if (threadIdx.x == 0 && blockIdx.x == 0) {
    double s = 0.0, s2 = 0.0;
    for (int p = 0; p < nw; ++p) {
      s += cd_part[p];
      s2 += cd2_part[p];
    }
    double mean = s / (double)C;
    double var = (s2 - s * s / (double)C) / (double)(C - 1);
    out[0] = (float)(mean / var / (double)N);
  }
}

extern "C" void kernel_launch(void* const* d_in, const int* in_sizes, int n_in,
                              void* d_out, int out_size, void* d_ws,
                              size_t ws_size, hipStream_t stream) {
  const float* centers = (const float*)d_in[0];
  const int C = in_sizes[0] / D;        // 4096
  const long long N = in_sizes[2];      // labels.shape[0] = 262144
  (void)n_in; (void)out_size;

  // Pick wave count from available scratch: bytes(nw) = nw*(D+1)*4 + nw*16.
  int nw = 128;
  while (nw > 16 && (size_t)nw * ((D + 1) * 4 + 16) > ws_size) nw >>= 1;

  char* ws = (char*)d_ws;
  float* t_part = (float*)ws;                              // nw*D floats
  float* S_part = (float*)(ws + (size_t)nw * D * 4);       // nw floats
  double* cd_part = (double*)(ws + (size_t)nw * (D + 1) * 4);  // 8B aligned
  double* cd2_part = cd_part + nw;

  dim3 grid(nw / 4), block(THREADS);
  hipLaunchKernelGGL(k1_colsum, grid, block, 0, stream, centers, t_part,
                     S_part, C, nw);
  hipLaunchKernelGGL(k2_cd, grid, block, 0, stream, centers, t_part, S_part,
                     cd_part, cd2_part, C, nw);
  hipLaunchKernelGGL(k3_final, dim3(1), dim3(64), 0, stream, cd_part, cd2_part,
                     (float*)d_out, C, N, nw);
}